// Round 3
// baseline (793.904 us; speedup 1.0000x reference)
//
#include <hip/hip_runtime.h>
#include <hip/hip_fp16.h>
#include <cstdint>
#include <cmath>

#define TOKENS  16384
#define HIDDEN  4096
#define NEXP    256
#define TOPK    8
#define KDROP   4   /* n_group - topk_group */

typedef _Float16 f16x8  __attribute__((ext_vector_type(8)));
typedef _Float16 f16x4  __attribute__((ext_vector_type(4)));
typedef float    f32x16 __attribute__((ext_vector_type(16)));
typedef float    f32x4  __attribute__((ext_vector_type(4)));

#define LO_SCALE 2048.0f          /* 2^11 */
#define LO_INV   (1.0f/2048.0f)

// ws layout (bytes):
//   [0, 2097152)             w_h  f16 chunk-array
//   [2097152, +2097152)      w_l  f16 chunk-array (scaled by 2^11)
#define WS_WH_OFF 0
#define WS_WL_OFF 2097152

// non-temporal loads: x / w are strictly streaming (zero reuse)
static __device__ __forceinline__ f32x4 ldnt4(const float* p) {
    return __builtin_nontemporal_load((const f32x4*)p);
}

// ---------------------------------------------------------------------------
// Pre-kernel: split w (fp32) into f16 hi / (lo*2^11) stored in MFMA-frag
// chunk order: chunk (e,k8grp) -> cid = ((kc*2+s)*8 + e/32)*64 + hl*32 + e%32
// where kc=k/32, s=(k/16)%2, hl=(k/8)%2.  Each chunk = 8 consecutive k f16.
// ---------------------------------------------------------------------------
__global__ __launch_bounds__(256)
void wsplit(const float* __restrict__ w, _Float16* __restrict__ wh,
            _Float16* __restrict__ wl)
{
    const int idx = blockIdx.x * 256 + threadIdx.x;   // 0..131071
    const int e   = idx >> 9;                         // expert 0..255
    const int kg8 = idx & 511;                        // 8-k group
    const float* p = w + (size_t)e * HIDDEN + kg8 * 8;
    f32x4 f0 = ldnt4(p);
    f32x4 f1 = ldnt4(p + 4);
    float v[8] = {f0.x, f0.y, f0.z, f0.w, f1.x, f1.y, f1.z, f1.w};
    f16x8 hi, lo;
    #pragma unroll
    for (int i = 0; i < 8; ++i) {
        _Float16 h = (_Float16)v[i];
        hi[i] = h;
        lo[i] = (_Float16)((v[i] - (float)h) * LO_SCALE);
    }
    const int kc = kg8 >> 2, s = (kg8 >> 1) & 1, hl = kg8 & 1;
    const int cid = ((kc * 2 + s) * 8 + (e >> 5)) * 64 + hl * 32 + (e & 31);
    ((f16x8*)wh)[cid] = hi;
    ((f16x8*)wl)[cid] = lo;
}

__device__ __forceinline__ unsigned ordkey(float f) {
    unsigned u = __float_as_uint(f);
    return (u & 0x80000000u) ? ~u : (u | 0x80000000u);  // monotone float->uint
}

// ---------------------------------------------------------------------------
// Fused GEMM + gating, K-split INSIDE the block for occupancy:
//   block = 32 tokens x 256 experts, 512 threads (8 waves).
//   waves 0-3: K-half 0 (k in [0,2048)), waves 4-7: K-half 1.
//   wave wv: experts [(wv&3)*64, +64), 1x2 MFMA tiles of 32x32.
//   2 blocks/CU (LDS 48 KB, VGPR ~<128) -> 16 waves/CU = 4 waves/SIMD.
// A double-buffered in LDS per half (one barrier/iter); B register-prefetched
// one iteration ahead from the chunk-ordered, L2-resident wh/wl.
// Epilogue: half-0 waves write raw gate partials to sigbuf, barrier, half-1
// waves add + sigmoid, barrier, all waves top-k (4 tokens each).
// ---------------------------------------------------------------------------
__global__ __launch_bounds__(512, 4)
void gemm_gate(const float* __restrict__ x, const _Float16* __restrict__ wh,
               const _Float16* __restrict__ wl,
               const float* __restrict__ bias, float* __restrict__ out)
{
    __shared__ _Float16 Ah[2][2][32 * 32];   // [half][dbuf] 2 KB each = 8 KB
    __shared__ _Float16 Al[2][2][32 * 32];   // 8 KB
    __shared__ float sigbuf[32 * 256];       // 32 KB

    const int tid  = threadIdx.x;
    const int wv   = tid >> 6;
    const int lane = tid & 63;
    const int h    = wv >> 2;      // K-half of this wave
    const int wq   = wv & 3;       // expert quad (64 experts)
    const int tok0 = blockIdx.x * 32;

    // A staging (tid < 256 only): thread stages one 8-k f16x8 chunk per half.
    //   sm = token 0..31, sq8 = 8-k group within the 64 k staged per iter
    //   (both halves), sh = which half's buffer, sq = 8-k group within 32 k.
    const int sm  = tid >> 3;          // 0..31 (tid<256)
    const int sq8 = tid & 7;           // 0..7
    const int sh  = sq8 >> 2;          // staged half
    const int sq  = sq8 & 3;           // 8-k group within the 32-k chunk
    const float* xr = x + (size_t)(tok0 + sm) * HIDDEN + sh * (HIDDEN / 2) + sq * 8;
    const int schunk = (sq >> 1) * 64 + (sq & 1) * 32 + sm;   // 16B-chunk index

    const f16x8* whc = (const f16x8*)wh;
    const f16x8* wlc = (const f16x8*)wl;

    f32x16 accH[2] = {};   // hi*hi               [ntile c]
    f32x16 accX[2] = {};   // lo*hi + hi*lo (x 2^11)

    f16x8 bh[2][2], bl[2][2];   // current iteration's B frags [kstep s][ntile c]

    const bool stager = (tid < 256);

    // ---- prologue: A(0) both halves -> LDS[.][0], B(0) -> regs
    {
        if (stager) {
            f32x4 f0 = ldnt4(xr);
            f32x4 f1 = ldnt4(xr + 4);
            float v[8] = {f0.x, f0.y, f0.z, f0.w, f1.x, f1.y, f1.z, f1.w};
            f16x8 hi, lo;
            #pragma unroll
            for (int i = 0; i < 8; ++i) {
                _Float16 hh = (_Float16)v[i];
                hi[i] = hh;
                lo[i] = (_Float16)((v[i] - (float)hh) * LO_SCALE);
            }
            *(f16x8*)&Ah[sh][0][schunk * 8] = hi;
            *(f16x8*)&Al[sh][0][schunk * 8] = lo;
        }
        const int kc = h * 64;
        #pragma unroll
        for (int s = 0; s < 2; ++s) {
            const int base = ((kc * 2 + s) * 8 + wq * 2) * 64 + lane;
            bh[s][0] = whc[base];
            bh[s][1] = whc[base + 64];
            bl[s][0] = wlc[base];
            bl[s][1] = wlc[base + 64];
        }
    }
    __syncthreads();

    #pragma unroll 2
    for (int i = 0; i < 64; ++i) {
        const int cur  = i & 1;
        const bool more = (i < 63);

        // ---- prefetch next iteration (A raw + B frags) into registers
        f32x4 a0n, a1n;
        f16x8 bhn[2][2], bln[2][2];
        if (more) {
            if (stager) {
                const float* ap = xr + (i + 1) * 32;
                a0n = ldnt4(ap);
                a1n = ldnt4(ap + 4);
            }
            const int kc = h * 64 + i + 1;
            #pragma unroll
            for (int s = 0; s < 2; ++s) {
                const int base = ((kc * 2 + s) * 8 + wq * 2) * 64 + lane;
                bhn[s][0] = whc[base];
                bhn[s][1] = whc[base + 64];
                bln[s][0] = wlc[base];
                bln[s][1] = wlc[base + 64];
            }
        }

        // ---- compute on LDS[h][cur] with current B regs (loaded last iter)
        #pragma unroll
        for (int s = 0; s < 2; ++s) {
            f16x8 ah = *(const f16x8*)&Ah[h][cur][(s * 64 + lane) * 8];
            f16x8 al = *(const f16x8*)&Al[h][cur][(s * 64 + lane) * 8];

            accH[0] = __builtin_amdgcn_mfma_f32_32x32x16_f16(ah, bh[s][0], accH[0], 0, 0, 0);
            accH[1] = __builtin_amdgcn_mfma_f32_32x32x16_f16(ah, bh[s][1], accH[1], 0, 0, 0);
            accX[0] = __builtin_amdgcn_mfma_f32_32x32x16_f16(al, bh[s][0], accX[0], 0, 0, 0);
            accX[1] = __builtin_amdgcn_mfma_f32_32x32x16_f16(al, bh[s][1], accX[1], 0, 0, 0);
            accX[0] = __builtin_amdgcn_mfma_f32_32x32x16_f16(ah, bl[s][0], accX[0], 0, 0, 0);
            accX[1] = __builtin_amdgcn_mfma_f32_32x32x16_f16(ah, bl[s][1], accX[1], 0, 0, 0);
        }

        // ---- store next A tile into the other LDS buffer; rotate B regs
        if (more) {
            if (stager) {
                float v[8] = {a0n.x, a0n.y, a0n.z, a0n.w, a1n.x, a1n.y, a1n.z, a1n.w};
                f16x8 hi, lo;
                #pragma unroll
                for (int ii = 0; ii < 8; ++ii) {
                    _Float16 hh = (_Float16)v[ii];
                    hi[ii] = hh;
                    lo[ii] = (_Float16)((v[ii] - (float)hh) * LO_SCALE);
                }
                *(f16x8*)&Ah[sh][cur ^ 1][schunk * 8] = hi;
                *(f16x8*)&Al[sh][cur ^ 1][schunk * 8] = lo;
            }
            #pragma unroll
            for (int s = 0; s < 2; ++s) {
                bh[s][0] = bhn[s][0]; bh[s][1] = bhn[s][1];
                bl[s][0] = bln[s][0]; bl[s][1] = bln[s][1];
            }
        }
        __syncthreads();
    }

    // ---- combine: half-0 writes raw partials, half-1 adds + sigmoid
    {
        const int col   = wq * 64 + (lane & 31);
        const int rbase = 4 * (lane >> 5);
        if (h == 0) {
            #pragma unroll
            for (int c = 0; c < 2; ++c)
                #pragma unroll
                for (int reg = 0; reg < 16; ++reg) {
                    const int row = (reg & 3) + 8 * (reg >> 2) + rbase;
                    sigbuf[row * NEXP + col + c * 32] = accH[c][reg] + accX[c][reg] * LO_INV;
                }
        }
        __syncthreads();
        if (h == 1) {
            #pragma unroll
            for (int c = 0; c < 2; ++c)
                #pragma unroll
                for (int reg = 0; reg < 16; ++reg) {
                    const int row = (reg & 3) + 8 * (reg >> 2) + rbase;
                    const float g = sigbuf[row * NEXP + col + c * 32]
                                  + accH[c][reg] + accX[c][reg] * LO_INV;
                    sigbuf[row * NEXP + col + c * 32] = 1.0f / (1.0f + expf(-g));
                }
        }
        __syncthreads();
    }

    // ---- in-block gating top-k: wave wv handles tokens [wv*4, wv*4+4)
    const float4 bv = ((const float4*)bias)[lane];
    for (int tt = 0; tt < 4; ++tt) {
        const int lt = wv * 4 + tt;          // local token
        const int t  = tok0 + lt;            // global token
        f32x4 sv = *(const f32x4*)&sigbuf[lt * NEXP + lane * 4];
        const float sig0 = sv.x, sig1 = sv.y, sig2 = sv.z, sig3 = sv.w;
        const float sc0 = sig0 + bv.x, sc1 = sig1 + bv.y;
        const float sc2 = sig2 + bv.z, sc3 = sig3 + bv.w;

        // top-2 of my 4 scores
        float m1 = fmaxf(sc0, sc1);
        float m2 = fminf(sc0, sc1);
        if (sc2 > m1) { m2 = m1; m1 = sc2; } else m2 = fmaxf(m2, sc2);
        if (sc3 > m1) { m2 = m1; m1 = sc3; } else m2 = fmaxf(m2, sc3);
        // merge across the 8 lanes of this group (group = lane>>3, 32 experts)
        #pragma unroll
        for (int off = 1; off < 8; off <<= 1) {
            float o1 = __shfl_xor(m1, off);
            float o2 = __shfl_xor(m2, off);
            float nm1 = fmaxf(m1, o1);
            float nm2 = fmaxf(fminf(m1, o1), fmaxf(m2, o2));
            m1 = nm1; m2 = nm2;
        }
        float gsum = m1 + m2;
        float gs[8];
        #pragma unroll
        for (int gi = 0; gi < 8; ++gi) gs[gi] = __shfl(gsum, gi * 8);

        // keep the KDROP smallest groups (tie -> lower index), faithful to ref
        int keepmask = 0;
        #pragma unroll
        for (int g = 0; g < 8; ++g) {
            int rank = 0;
            #pragma unroll
            for (int hh = 0; hh < 8; ++hh)
                rank += (gs[hh] < gs[g]) || (gs[hh] == gs[g] && hh < g);
            if (rank < KDROP) keepmask |= (1 << g);
        }
        const bool kept = (keepmask >> (lane >> 3)) & 1;

        // lexicographic (value asc, index asc) keys; masked entries = +0.0
        const unsigned ib = (unsigned)(lane * 4);
        unsigned long long k0 = ((unsigned long long)ordkey(kept ? sc0 : 0.0f) << 32) | (ib + 0);
        unsigned long long k1 = ((unsigned long long)ordkey(kept ? sc1 : 0.0f) << 32) | (ib + 1);
        unsigned long long k2 = ((unsigned long long)ordkey(kept ? sc2 : 0.0f) << 32) | (ib + 2);
        unsigned long long k3 = ((unsigned long long)ordkey(kept ? sc3 : 0.0f) << 32) | (ib + 3);

        float ssum = 0.0f, myval = 0.0f;
        int myidx = 0;
        #pragma unroll
        for (int r = 0; r < TOPK; ++r) {
            unsigned long long kmin = k0 < k1 ? k0 : k1;
            if (k2 < kmin) kmin = k2;
            if (k3 < kmin) kmin = k3;
            #pragma unroll
            for (int off = 32; off >= 1; off >>= 1) {
                unsigned long long o = __shfl_xor(kmin, off);
                if (o < kmin) kmin = o;
            }
            const int id   = (int)(kmin & 0xffffffffull);
            const int src  = id >> 2;   // owning lane (wave-uniform)
            const int slot = id & 3;    // wave-uniform
            float vsrc = (slot == 0) ? sig0 : (slot == 1) ? sig1
                       : (slot == 2) ? sig2 : sig3;
            float v = __shfl(vsrc, src);
            ssum += v;
            if (lane == r) { myidx = id; myval = v; }
            const bool mine = (lane == src);
            if (mine && slot == 0) k0 = ~0ull;
            if (mine && slot == 1) k1 = ~0ull;
            if (mine && slot == 2) k2 = ~0ull;
            if (mine && slot == 3) k3 = ~0ull;
        }

        if (lane < TOPK) {
            out[(size_t)t * TOPK + lane] = (float)myidx;                      // inds
            out[(size_t)TOKENS * TOPK + (size_t)t * TOPK + lane] =
                myval / (ssum + 1e-20f) * 2.5f;                               // sel
        }
    }
}

// ---------------------------------------------------------------------------
extern "C" void kernel_launch(void* const* d_in, const int* in_sizes, int n_in,
                              void* d_out, int out_size, void* d_ws, size_t ws_size,
                              hipStream_t stream)
{
    const float* x    = (const float*)d_in[0];
    const float* w    = (const float*)d_in[1];
    const float* bias = (const float*)d_in[2];
    float* out = (float*)d_out;

    _Float16*  wh = (_Float16*)((char*)d_ws + WS_WH_OFF);
    _Float16*  wl = (_Float16*)((char*)d_ws + WS_WL_OFF);

    // split w into chunk-ordered f16 hi/lo
    wsplit<<<dim3(512), dim3(256), 0, stream>>>(w, wh, wl);
    // fused split-f16 MFMA GEMM (in-block K-split) + sigmoid + in-block top-k
    gemm_gate<<<dim3(TOKENS / 32), dim3(512), 0, stream>>>(x, wh, wl, bias, out);
}

// Round 4
// 440.128 us; speedup vs baseline: 1.8038x; 1.8038x over previous
//
#include <hip/hip_runtime.h>
#include <hip/hip_fp16.h>
#include <cstdint>
#include <cmath>

#define TOKENS  16384
#define HIDDEN  4096
#define NEXP    256
#define TOPK    8
#define KDROP   4   /* n_group - topk_group */

typedef _Float16 f16x8  __attribute__((ext_vector_type(8)));
typedef float    f32x16 __attribute__((ext_vector_type(16)));
typedef float    f32x4  __attribute__((ext_vector_type(4)));

#define LO_SCALE 2048.0f          /* 2^11 */
#define LO_INV   (1.0f/2048.0f)

// ws layout (bytes):
//   [0, 16777216)            gates0 fp32 [TOKENS][NEXP]   (K-half 0)
//   [16777216, +16777216)    gates1 fp32 [TOKENS][NEXP]   (K-half 1)
//   [33554432, +2097152)     w_h  f16 chunk-array
//   [35651584, +2097152)     w_l  f16 chunk-array (scaled by 2^11)
#define WS_G0_OFF 0
#define WS_G1_OFF 16777216
#define WS_WH_OFF 33554432
#define WS_WL_OFF 35651584

// ---------------------------------------------------------------------------
// Pre-kernel: split w (fp32) into f16 hi / (lo*2^11) stored in MFMA-frag
// chunk order: chunk (e,k8grp) -> cid = ((kc*2+s)*8 + e/32)*64 + hl*32 + e%32
// where kc=k/32, s=(k/16)%2, hl=(k/8)%2.  Each chunk = 8 consecutive k f16.
// ---------------------------------------------------------------------------
__global__ __launch_bounds__(256)
void wsplit(const float* __restrict__ w, _Float16* __restrict__ wh,
            _Float16* __restrict__ wl)
{
    const int idx = blockIdx.x * 256 + threadIdx.x;   // 0..131071
    const int e   = idx >> 9;                         // expert 0..255
    const int kg8 = idx & 511;                        // 8-k group
    const float4* p = (const float4*)(w + (size_t)e * HIDDEN + kg8 * 8);
    float4 f0 = p[0], f1 = p[1];
    float v[8] = {f0.x, f0.y, f0.z, f0.w, f1.x, f1.y, f1.z, f1.w};
    f16x8 hi, lo;
    #pragma unroll
    for (int i = 0; i < 8; ++i) {
        _Float16 h = (_Float16)v[i];
        hi[i] = h;
        lo[i] = (_Float16)((v[i] - (float)h) * LO_SCALE);
    }
    const int kc = kg8 >> 2, s = (kg8 >> 1) & 1, hl = kg8 & 1;
    const int cid = ((kc * 2 + s) * 8 + (e >> 5)) * 64 + hl * 32 + (e & 31);
    ((f16x8*)wh)[cid] = hi;
    ((f16x8*)wl)[cid] = lo;
}

// ---------------------------------------------------------------------------
// GEMM: gates_half = x @ W^T (one K-half per block) via split-f16 MFMA.
// 128-token tile: block = 128 tokens x 256 experts x one K-half.
// Grid 256 flat (y = bid&1 -> K-half), 512 threads (8 waves), 1 block/CU.
//   wave w: token-half (w>>2)*64, experts [(w&3)*64, +64), 2x2 32x32 tiles.
// B register-prefetched 1 iter ahead from chunk-ordered L2-resident wh/wl
// (traffic halves vs 64-token tile: 256 blocks x 2 MB = 512 MB of L2).
// A staged through LDS with a 2-DEEP global prefetch: loads for kc+2 are
// issued at iter kc, converted+written at iter kc+1 -> ~2-iter in-flight
// window covers HBM latency instead of stalling every barrier.
// ---------------------------------------------------------------------------
__global__ __launch_bounds__(512, 2)
void gemm_split(const float* __restrict__ x, const _Float16* __restrict__ wh,
                const _Float16* __restrict__ wl,
                float* __restrict__ g0, float* __restrict__ g1)
{
    __shared__ _Float16 Ah[2][2][64 * 32];   // [dbuf][tokhalf] 4 KB each
    __shared__ _Float16 Al[2][2][64 * 32];   // total 32 KB

    const int tid  = threadIdx.x;
    const int w    = tid >> 6;
    const int lane = tid & 63;
    const int th   = w >> 2;       // token-half this wave computes
    const int wq   = w & 3;        // expert quad (64 experts)

    const int bid  = blockIdx.x;         // 0..255
    const int y    = bid & 1;            // K-half
    const int tok0 = (bid >> 1) * 128;
    const int kcg0 = y * 64;             // first 32-k chunk of this K-half
    float* gates_half = y ? g1 : g0;

    // A staging: thread t loads one 8-k chunk of one token row (512 thr = 128x32)
    const int stok = tid >> 2;           // token 0..127
    const int sq   = tid & 3;            // 8-k group within the 32-k chunk
    const int sth  = stok >> 6;          // staged token-half
    const int sm   = stok & 63;          // token within half
    const float* xr = x + (size_t)(tok0 + stok) * HIDDEN + (size_t)kcg0 * 32 + sq * 8;
    const int scid = ((sq >> 1) * 2 + (sm >> 5)) * 64 + (sq & 1) * 32 + (sm & 31);

    const f16x8* whc = (const f16x8*)wh;
    const f16x8* wlc = (const f16x8*)wl;

    f32x16 accH[2][2] = {};   // hi*hi                [row r][ntile c]
    f32x16 accX[2][2] = {};   // lo*hi + hi*lo (x 2^11)

    f16x8 bh[2][2], bl[2][2];   // current iteration's B frags [kstep s][ntile c]
    f32x4 aM0, aM1;             // A data for iter kc+1 (in regs)

    // ---- prologue: A(0) -> LDS[0]; A(1) in-flight to regs; B(0) -> regs
    {
        f32x4 f0 = *(const f32x4*)(xr);
        f32x4 f1 = *(const f32x4*)(xr + 4);
        aM0 = *(const f32x4*)(xr + 32);          // kc=1, issued early
        aM1 = *(const f32x4*)(xr + 36);
        #pragma unroll
        for (int s = 0; s < 2; ++s) {
            const int base = ((kcg0 * 2 + s) * 8 + wq * 2) * 64 + lane;
            bh[s][0] = whc[base];
            bh[s][1] = whc[base + 64];
            bl[s][0] = wlc[base];
            bl[s][1] = wlc[base + 64];
        }
        float v[8] = {f0.x, f0.y, f0.z, f0.w, f1.x, f1.y, f1.z, f1.w};
        f16x8 hi, lo;
        #pragma unroll
        for (int i = 0; i < 8; ++i) {
            _Float16 h = (_Float16)v[i];
            hi[i] = h;
            lo[i] = (_Float16)((v[i] - (float)h) * LO_SCALE);
        }
        *(f16x8*)&Ah[0][sth][scid * 8] = hi;
        *(f16x8*)&Al[0][sth][scid * 8] = lo;
    }
    __syncthreads();

    #pragma unroll 2
    for (int kc = 0; kc < 64; ++kc) {
        const int cur = kc & 1;

        // ---- issue A load for kc+2 (2-deep) and B frags for kc+1 (1-deep)
        f32x4 aN0, aN1;
        f16x8 bhn[2][2], bln[2][2];
        if (kc + 2 < 64) {
            const float* ap = xr + (kc + 2) * 32;
            aN0 = *(const f32x4*)(ap);
            aN1 = *(const f32x4*)(ap + 4);
        }
        if (kc + 1 < 64) {
            const int kcg = kcg0 + kc + 1;
            #pragma unroll
            for (int s = 0; s < 2; ++s) {
                const int base = ((kcg * 2 + s) * 8 + wq * 2) * 64 + lane;
                bhn[s][0] = whc[base];
                bhn[s][1] = whc[base + 64];
                bln[s][0] = wlc[base];
                bln[s][1] = wlc[base + 64];
            }
        }

        // ---- compute on LDS[cur][th] with current B regs
        #pragma unroll
        for (int s = 0; s < 2; ++s) {
            f16x8 ah0 = *(const f16x8*)&Ah[cur][th][((s * 2 + 0) * 64 + lane) * 8];
            f16x8 ah1 = *(const f16x8*)&Ah[cur][th][((s * 2 + 1) * 64 + lane) * 8];
            f16x8 al0 = *(const f16x8*)&Al[cur][th][((s * 2 + 0) * 64 + lane) * 8];
            f16x8 al1 = *(const f16x8*)&Al[cur][th][((s * 2 + 1) * 64 + lane) * 8];

            accH[0][0] = __builtin_amdgcn_mfma_f32_32x32x16_f16(ah0, bh[s][0], accH[0][0], 0, 0, 0);
            accH[0][1] = __builtin_amdgcn_mfma_f32_32x32x16_f16(ah0, bh[s][1], accH[0][1], 0, 0, 0);
            accH[1][0] = __builtin_amdgcn_mfma_f32_32x32x16_f16(ah1, bh[s][0], accH[1][0], 0, 0, 0);
            accH[1][1] = __builtin_amdgcn_mfma_f32_32x32x16_f16(ah1, bh[s][1], accH[1][1], 0, 0, 0);
            accX[0][0] = __builtin_amdgcn_mfma_f32_32x32x16_f16(al0, bh[s][0], accX[0][0], 0, 0, 0);
            accX[0][1] = __builtin_amdgcn_mfma_f32_32x32x16_f16(al0, bh[s][1], accX[0][1], 0, 0, 0);
            accX[1][0] = __builtin_amdgcn_mfma_f32_32x32x16_f16(al1, bh[s][0], accX[1][0], 0, 0, 0);
            accX[1][1] = __builtin_amdgcn_mfma_f32_32x32x16_f16(al1, bh[s][1], accX[1][1], 0, 0, 0);
            accX[0][0] = __builtin_amdgcn_mfma_f32_32x32x16_f16(ah0, bl[s][0], accX[0][0], 0, 0, 0);
            accX[0][1] = __builtin_amdgcn_mfma_f32_32x32x16_f16(ah0, bl[s][1], accX[0][1], 0, 0, 0);
            accX[1][0] = __builtin_amdgcn_mfma_f32_32x32x16_f16(ah1, bl[s][0], accX[1][0], 0, 0, 0);
            accX[1][1] = __builtin_amdgcn_mfma_f32_32x32x16_f16(ah1, bl[s][1], accX[1][1], 0, 0, 0);
        }

        // ---- write A(kc+1) (loaded last iter) into the other buffer; rotate
        if (kc + 1 < 64) {
            float v[8] = {aM0.x, aM0.y, aM0.z, aM0.w, aM1.x, aM1.y, aM1.z, aM1.w};
            f16x8 hi, lo;
            #pragma unroll
            for (int i = 0; i < 8; ++i) {
                _Float16 h = (_Float16)v[i];
                hi[i] = h;
                lo[i] = (_Float16)((v[i] - (float)h) * LO_SCALE);
            }
            *(f16x8*)&Ah[cur ^ 1][sth][scid * 8] = hi;
            *(f16x8*)&Al[cur ^ 1][sth][scid * 8] = lo;
            aM0 = aN0; aM1 = aN1;
            #pragma unroll
            for (int s = 0; s < 2; ++s) {
                bh[s][0] = bhn[s][0]; bh[s][1] = bhn[s][1];
                bl[s][0] = bln[s][0]; bl[s][1] = bln[s][1];
            }
        }
        __syncthreads();
    }

    // ---- epilogue: combine hi + lo*2^-11, plain stores
    const int col   = lane & 31;
    const int rbase = 4 * (lane >> 5);
    #pragma unroll
    for (int r = 0; r < 2; ++r)
        #pragma unroll
        for (int c = 0; c < 2; ++c) {
            float* gp = gates_half + (size_t)(tok0 + th * 64 + r * 32) * NEXP
                      + wq * 64 + c * 32 + col;
            #pragma unroll
            for (int reg = 0; reg < 16; ++reg) {
                const int row = (reg & 3) + 8 * (reg >> 2) + rbase;
                gp[(size_t)row * NEXP] = accH[r][c][reg] + accX[r][c][reg] * LO_INV;
            }
        }
}

// ---------------------------------------------------------------------------
// Gating epilogue: one wave per token; sums the two K-half gate buffers.
// All-register top-k (no dynamic array indexing -> no scratch).
// ---------------------------------------------------------------------------
__device__ __forceinline__ unsigned ordkey(float f) {
    unsigned u = __float_as_uint(f);
    return (u & 0x80000000u) ? ~u : (u | 0x80000000u);  // monotone float->uint
}

__global__ __launch_bounds__(256, 4)
void gate_epilogue(const float* __restrict__ g0,
                   const float* __restrict__ g1,
                   const float* __restrict__ bias,
                   float* __restrict__ out)
{
    const int tid  = threadIdx.x;
    const int wv   = tid >> 6;
    const int lane = tid & 63;
    const int t    = blockIdx.x * 4 + wv;

    float4 ga = ((const float4*)(g0 + (size_t)t * NEXP))[lane];
    float4 gb = ((const float4*)(g1 + (size_t)t * NEXP))[lane];
    float4 bv = ((const float4*)bias)[lane];
    float4 gv = make_float4(ga.x + gb.x, ga.y + gb.y, ga.z + gb.z, ga.w + gb.w);

    float sig0 = 1.0f / (1.0f + expf(-gv.x));
    float sig1 = 1.0f / (1.0f + expf(-gv.y));
    float sig2 = 1.0f / (1.0f + expf(-gv.z));
    float sig3 = 1.0f / (1.0f + expf(-gv.w));
    float sc0 = sig0 + bv.x, sc1 = sig1 + bv.y;
    float sc2 = sig2 + bv.z, sc3 = sig3 + bv.w;

    // top-2 of my 4 scores
    float m1 = fmaxf(sc0, sc1);
    float m2 = fminf(sc0, sc1);
    if (sc2 > m1) { m2 = m1; m1 = sc2; } else m2 = fmaxf(m2, sc2);
    if (sc3 > m1) { m2 = m1; m1 = sc3; } else m2 = fmaxf(m2, sc3);
    // merge across the 8 lanes of this group (group = lane>>3, 32 experts)
    #pragma unroll
    for (int off = 1; off < 8; off <<= 1) {
        float o1 = __shfl_xor(m1, off);
        float o2 = __shfl_xor(m2, off);
        float nm1 = fmaxf(m1, o1);
        float nm2 = fmaxf(fminf(m1, o1), fmaxf(m2, o2));
        m1 = nm1; m2 = nm2;
    }
    float gsum = m1 + m2;
    float gs[8];
    #pragma unroll
    for (int gi = 0; gi < 8; ++gi) gs[gi] = __shfl(gsum, gi * 8);

    // keep the KDROP smallest groups (tie -> lower index), faithful to ref
    int keepmask = 0;
    #pragma unroll
    for (int g = 0; g < 8; ++g) {
        int rank = 0;
        #pragma unroll
        for (int h = 0; h < 8; ++h)
            rank += (gs[h] < gs[g]) || (gs[h] == gs[g] && h < g);
        if (rank < KDROP) keepmask |= (1 << g);
    }
    const bool kept = (keepmask >> (lane >> 3)) & 1;

    // lexicographic (value asc, index asc) keys; masked entries = +0.0
    const unsigned ib = (unsigned)(lane * 4);
    unsigned long long k0 = ((unsigned long long)ordkey(kept ? sc0 : 0.0f) << 32) | (ib + 0);
    unsigned long long k1 = ((unsigned long long)ordkey(kept ? sc1 : 0.0f) << 32) | (ib + 1);
    unsigned long long k2 = ((unsigned long long)ordkey(kept ? sc2 : 0.0f) << 32) | (ib + 2);
    unsigned long long k3 = ((unsigned long long)ordkey(kept ? sc3 : 0.0f) << 32) | (ib + 3);

    float ssum = 0.0f, myval = 0.0f;
    int myidx = 0;
    #pragma unroll
    for (int r = 0; r < TOPK; ++r) {
        unsigned long long kmin = k0 < k1 ? k0 : k1;
        if (k2 < kmin) kmin = k2;
        if (k3 < kmin) kmin = k3;
        #pragma unroll
        for (int off = 32; off >= 1; off >>= 1) {
            unsigned long long o = __shfl_xor(kmin, off);
            if (o < kmin) kmin = o;
        }
        const int id   = (int)(kmin & 0xffffffffull);
        const int src  = id >> 2;   // owning lane (wave-uniform)
        const int slot = id & 3;    // wave-uniform
        float vsrc = (slot == 0) ? sig0 : (slot == 1) ? sig1
                   : (slot == 2) ? sig2 : sig3;
        float v = __shfl(vsrc, src);
        ssum += v;
        if (lane == r) { myidx = id; myval = v; }
        const bool mine = (lane == src);
        if (mine && slot == 0) k0 = ~0ull;
        if (mine && slot == 1) k1 = ~0ull;
        if (mine && slot == 2) k2 = ~0ull;
        if (mine && slot == 3) k3 = ~0ull;
    }

    if (lane < TOPK) {
        out[(size_t)t * TOPK + lane] = (float)myidx;                      // inds
        out[(size_t)TOKENS * TOPK + (size_t)t * TOPK + lane] =
            myval / (ssum + 1e-20f) * 2.5f;                               // sel
    }
}

// ---------------------------------------------------------------------------
extern "C" void kernel_launch(void* const* d_in, const int* in_sizes, int n_in,
                              void* d_out, int out_size, void* d_ws, size_t ws_size,
                              hipStream_t stream)
{
    const float* x    = (const float*)d_in[0];
    const float* w    = (const float*)d_in[1];
    const float* bias = (const float*)d_in[2];
    float* out = (float*)d_out;

    float*     g0 = (float*)((char*)d_ws + WS_G0_OFF);
    float*     g1 = (float*)((char*)d_ws + WS_G1_OFF);
    _Float16*  wh = (_Float16*)((char*)d_ws + WS_WH_OFF);
    _Float16*  wl = (_Float16*)((char*)d_ws + WS_WL_OFF);

    // split w into chunk-ordered f16 hi/lo
    wsplit<<<dim3(512), dim3(256), 0, stream>>>(w, wh, wl);
    // split-f16 MFMA GEMM, 128-token tile, K-split 2, 2-deep A prefetch
    gemm_split<<<dim3(256), dim3(512), 0, stream>>>(x, wh, wl, g0, g1);
    // gating epilogue sums the halves
    gate_epilogue<<<dim3(TOKENS / 4), dim3(256), 0, stream>>>(g0, g1, bias, out);
}